// Round 3
// baseline (1862.035 us; speedup 1.0000x reference)
//
#include <hip/hip_runtime.h>
#include <math.h>

#define D 120
#define GNUM 2048
#define RSE 15
#define BK 24
#define BKQ 6   // BK/4 float4 quads per chunk-row

__device__ __forceinline__ float sigmoidf_(float x) {
    return 1.0f / (1.0f + __expf(-x));
}
__device__ __forceinline__ float tanhf_(float x) {
    return 1.0f - 2.0f / (1.0f + __expf(2.0f * x));
}

// start[g] = first index i with seg[i] >= g (seg sorted ascending); start[G] = n
__global__ void offsets_kernel(const int* __restrict__ seg, int n, int* __restrict__ start) {
    int g = blockIdx.x * blockDim.x + threadIdx.x;
    if (g > GNUM) return;
    int lo = 0, hi = n;
    while (lo < hi) {
        int mid = (lo + hi) >> 1;
        if (seg[mid] < g) lo = mid + 1; else hi = mid;
    }
    start[g] = lo;
}

// C[M][120] = act(A[M][120]) @ W^T[120][120] (+bias); MODE 0: plain store.
// MODE 1: input tanh, epilogue highway vs a=ahw[seg[n]].
// BM=128, BN=128(120), BK=24 K-chunks; LDS 25.3 KB -> 4 blocks/CU.
template <int MODE>
__global__ __launch_bounds__(256, 4)
void gemm_lin(const float* __restrict__ A, const float* __restrict__ W,
              const float* __restrict__ bias, float* __restrict__ Cout, int M,
              const float* __restrict__ ahw, const int* __restrict__ seg) {
    __shared__ float at_[BK][132];  // [k][n]
    __shared__ float wt_[BK][132];  // [k][c]
    int tid = threadIdx.x;
    int tc = tid & 15, tr = tid >> 4;
    int nbase = blockIdx.x * 128;
    int an = tr * 8, c0 = tc * 4;

    float acc[8][8];
#pragma unroll
    for (int i = 0; i < 8; ++i)
#pragma unroll
        for (int j = 0; j < 8; ++j) acc[i][j] = 0.0f;

    for (int kc = 0; kc < D; kc += BK) {
        __syncthreads();
        // stage A chunk transposed; n-fastest -> conflict-free LDS writes
        for (int it = tid; it < 128 * BKQ; it += 256) {
            int n = it & 127, qq = it >> 7;
            int gn = nbase + n;
            float4 v = make_float4(0.f, 0.f, 0.f, 0.f);
            if (gn < M) v = *(const float4*)&A[(size_t)gn * D + kc + qq * 4];
            if (MODE == 1) { v.x = tanhf_(v.x); v.y = tanhf_(v.y); v.z = tanhf_(v.z); v.w = tanhf_(v.w); }
            int k = qq * 4;
            at_[k][n] = v.x; at_[k + 1][n] = v.y; at_[k + 2][n] = v.z; at_[k + 3][n] = v.w;
        }
        // stage W chunk transposed
        for (int it = tid; it < 128 * BKQ; it += 256) {
            int c = it & 127, qq = it >> 7;
            float4 v = make_float4(0.f, 0.f, 0.f, 0.f);
            if (c < D) v = *(const float4*)&W[c * D + kc + qq * 4];
            int k = qq * 4;
            wt_[k][c] = v.x; wt_[k + 1][c] = v.y; wt_[k + 2][c] = v.z; wt_[k + 3][c] = v.w;
        }
        __syncthreads();
#pragma unroll
        for (int k = 0; k < BK; ++k) {
            float4 a0 = *(const float4*)&at_[k][an];
            float4 a1 = *(const float4*)&at_[k][an + 4];
            float4 w0 = *(const float4*)&wt_[k][c0];
            float4 w1 = *(const float4*)&wt_[k][64 + c0];
            float av[8] = {a0.x, a0.y, a0.z, a0.w, a1.x, a1.y, a1.z, a1.w};
            float wv[8] = {w0.x, w0.y, w0.z, w0.w, w1.x, w1.y, w1.z, w1.w};
#pragma unroll
            for (int i = 0; i < 8; ++i)
#pragma unroll
                for (int j = 0; j < 8; ++j) acc[i][j] += av[i] * wv[j];
        }
    }

    float bv[8];
#pragma unroll
    for (int j = 0; j < 4; ++j) bv[j] = bias[c0 + j];
#pragma unroll
    for (int j = 0; j < 4; ++j) {
        int c = 64 + c0 + j;
        bv[4 + j] = (c < D) ? bias[c] : 0.0f;
    }

#pragma unroll
    for (int i = 0; i < 8; ++i) {
        int gn = nbase + an + i;
        if (gn >= M) continue;
        if (MODE == 0) {
            *(float4*)&Cout[(size_t)gn * D + c0] =
                make_float4(acc[i][0] + bv[0], acc[i][1] + bv[1], acc[i][2] + bv[2], acc[i][3] + bv[3]);
            if (tc < 14) {
                *(float4*)&Cout[(size_t)gn * D + 64 + c0] =
                    make_float4(acc[i][4] + bv[4], acc[i][5] + bv[5], acc[i][6] + bv[6], acc[i][7] + bv[7]);
            }
        } else {
            int g = seg[gn];
            const float* ag = ahw + (size_t)g * D;
            float4 a4 = *(const float4*)&ag[c0];
            float aa[4] = {a4.x, a4.y, a4.z, a4.w};
            float o[4];
#pragma unroll
            for (int j = 0; j < 4; ++j) {
                float b = acc[i][j] + bv[j];
                float z = sigmoidf_(aa[j] + b);
                o[j] = z * b + (1.0f - z) * aa[j];
            }
            *(float4*)&Cout[(size_t)gn * D + c0] = make_float4(o[0], o[1], o[2], o[3]);
            if (tc < 14) {
                float4 a4b = *(const float4*)&ag[64 + c0];
                float ab[4] = {a4b.x, a4b.y, a4b.z, a4b.w};
#pragma unroll
                for (int j = 0; j < 4; ++j) {
                    float b = acc[i][4 + j] + bv[4 + j];
                    float z = sigmoidf_(ab[j] + b);
                    o[j] = z * b + (1.0f - z) * ab[j];
                }
                *(float4*)&Cout[(size_t)gn * D + 64 + c0] = make_float4(o[0], o[1], o[2], o[3]);
            }
        }
    }
}

// Per-graph: channel average of s -> SE MLP -> w[g][120]
__global__ __launch_bounds__(128)
void se_kernel(const float* __restrict__ s, const int* __restrict__ start,
               const float* __restrict__ Wse1, const float* __restrict__ Wse2,
               float* __restrict__ wout) {
    int g = blockIdx.x;
    int i0 = start[g], i1 = start[g + 1];
    int t = threadIdx.x;
    __shared__ float avg_[D];
    __shared__ float t_[RSE];
    if (t < D) {
        float sum = 0.0f;
        for (int i = i0; i < i1; ++i) sum += s[(size_t)i * D + t];
        float cnt = (float)(i1 - i0);
        avg_[t] = sum / fmaxf(cnt, 1.0f);
    }
    __syncthreads();
    if (t < RSE) {
        float a = 0.0f;
        for (int j = 0; j < D; ++j) a += avg_[j] * Wse1[t * D + j];
        t_[t] = fmaxf(a, 0.0f);
    }
    __syncthreads();
    if (t < D) {
        float a = 0.0f;
#pragma unroll
        for (int k = 0; k < RSE; ++k) a += t_[k] * Wse2[t * RSE + k];
        wout[(size_t)g * D + t] = sigmoidf_(a);
    }
}

// Per-graph: A = sum s_i*mean_c(s_i*w), B = sum sigmoid(s_i), pooled = A*B
__global__ __launch_bounds__(256)
void pool_kernel(const float* __restrict__ s, const int* __restrict__ start,
                 const float* __restrict__ wse, float* __restrict__ pooled) {
    int g = blockIdx.x;
    int i0 = start[g], i1 = start[g + 1];
    int t = threadIdx.x;
    int lane = t & 63, wv = t >> 6;
    __shared__ float wl_[D];
    __shared__ float red_[8][D];
    if (t < D) wl_[t] = wse[(size_t)g * D + t];
    __syncthreads();
    float w0 = wl_[lane];
    float w1 = (lane < D - 64) ? wl_[lane + 64] : 0.0f;
    float A0 = 0, A1 = 0, B0 = 0, B1 = 0;
    for (int i = i0 + wv; i < i1; i += 4) {
        const float* row = s + (size_t)i * D;
        float s0 = row[lane];
        float s1 = (lane < D - 64) ? row[lane + 64] : 0.0f;
        float d = s0 * w0 + s1 * w1;
#pragma unroll
        for (int off = 32; off > 0; off >>= 1) d += __shfl_xor(d, off);
        float m = d * (1.0f / D);
        A0 += s0 * m;
        A1 += s1 * m;
        B0 += sigmoidf_(s0);
        B1 += sigmoidf_(s1);
    }
    red_[wv][lane] = A0;
    red_[4 + wv][lane] = B0;
    if (lane < D - 64) {
        red_[wv][lane + 64] = A1;
        red_[4 + wv][lane + 64] = B1;
    }
    __syncthreads();
    if (t < D) {
        float A = red_[0][t] + red_[1][t] + red_[2][t] + red_[3][t];
        float B = red_[4][t] + red_[5][t] + red_[6][t] + red_[7][t];
        pooled[(size_t)g * D + t] = A * B;
    }
}

// Fused GRU, K-chunked. Phase rz: K=240 concat [vbl|h] x 240 cols (r,z fused);
// phase h_n: K=120 over h; phase i_n: K=120 over vbl; epilogue combines.
// BM=64 rows/block; LDS ~30 KB.
__global__ __launch_bounds__(256, 3)
void gru_kernel(const float* __restrict__ vbl, const float* __restrict__ h,
                const float* __restrict__ wih, const float* __restrict__ whh,
                const float* __restrict__ bih, const float* __restrict__ bhh,
                float* __restrict__ out, int M) {
    __shared__ float atg_[BK][68];   // [k][n], n<64
    __shared__ float wts_[BK][248];  // [k][c], c<240 (rz) or c<120 (n-phases)
    int tid = threadIdx.x;
    int tc = tid & 15, tr = tid >> 4;
    int nbase = blockIdx.x * 64;
    int an = tr * 4, c0 = tc * 4;

    int cch[8];
    bool cval[8];
#pragma unroll
    for (int j = 0; j < 8; ++j) {
        int c = (j < 4) ? (c0 + j) : (64 + c0 + (j - 4));
        cch[j] = c;
        cval[j] = (c < D);
    }

    // ---------------- phase 1: fused r,z (K=240, N=240) ----------------
    float acc[4][16];
#pragma unroll
    for (int i = 0; i < 4; ++i)
#pragma unroll
        for (int j = 0; j < 16; ++j) acc[i][j] = 0.0f;

    for (int kc = 0; kc < 2 * D; kc += BK) {
        __syncthreads();
        for (int it = tid; it < 64 * BKQ; it += 256) {
            int n = it & 63, qq = it >> 6;
            int gn = nbase + n;
            int kk = kc + qq * 4;
            float4 v = make_float4(0.f, 0.f, 0.f, 0.f);
            if (gn < M)
                v = (kk < D) ? *(const float4*)&vbl[(size_t)gn * D + kk]
                             : *(const float4*)&h[(size_t)gn * D + kk - D];
            int k = qq * 4;
            atg_[k][n] = v.x; atg_[k + 1][n] = v.y; atg_[k + 2][n] = v.z; atg_[k + 3][n] = v.w;
        }
        for (int it = tid; it < 240 * BKQ; it += 256) {
            int cc = it % 240, qq = it / 240;
            int kk = kc + qq * 4;
            float4 v = (kk < D) ? *(const float4*)&wih[cc * D + kk]
                                : *(const float4*)&whh[cc * D + kk - D];
            int k = qq * 4;
            wts_[k][cc] = v.x; wts_[k + 1][cc] = v.y; wts_[k + 2][cc] = v.z; wts_[k + 3][cc] = v.w;
        }
        __syncthreads();
#pragma unroll
        for (int k = 0; k < BK; ++k) {
            float4 a0 = *(const float4*)&atg_[k][an];
            float4 w0 = *(const float4*)&wts_[k][c0];
            float4 w1 = *(const float4*)&wts_[k][64 + c0];
            float4 w2 = *(const float4*)&wts_[k][120 + c0];
            float4 w3 = *(const float4*)&wts_[k][184 + c0];
            float av[4] = {a0.x, a0.y, a0.z, a0.w};
            float wv[16] = {w0.x, w0.y, w0.z, w0.w, w1.x, w1.y, w1.z, w1.w,
                            w2.x, w2.y, w2.z, w2.w, w3.x, w3.y, w3.z, w3.w};
#pragma unroll
            for (int i = 0; i < 4; ++i)
#pragma unroll
                for (int j = 0; j < 16; ++j) acc[i][j] += av[i] * wv[j];
        }
    }

    float r[4][8], zz[4][8];
#pragma unroll
    for (int j = 0; j < 8; ++j) {
        float br = cval[j] ? (bih[cch[j]] + bhh[cch[j]]) : 0.0f;
        float bz = cval[j] ? (bih[D + cch[j]] + bhh[D + cch[j]]) : 0.0f;
#pragma unroll
        for (int i = 0; i < 4; ++i) {
            r[i][j] = sigmoidf_(acc[i][j] + br);
            zz[i][j] = sigmoidf_(acc[i][j + 8] + bz);
        }
    }

    // ---------------- phase 2: h_n (K=120 over h) ----------------
    float accn[4][8];
#pragma unroll
    for (int i = 0; i < 4; ++i)
#pragma unroll
        for (int j = 0; j < 8; ++j) accn[i][j] = 0.0f;

    const float* whn = whh + 2 * D * D;
    for (int kc = 0; kc < D; kc += BK) {
        __syncthreads();
        for (int it = tid; it < 64 * BKQ; it += 256) {
            int n = it & 63, qq = it >> 6;
            int gn = nbase + n;
            float4 v = make_float4(0.f, 0.f, 0.f, 0.f);
            if (gn < M) v = *(const float4*)&h[(size_t)gn * D + kc + qq * 4];
            int k = qq * 4;
            atg_[k][n] = v.x; atg_[k + 1][n] = v.y; atg_[k + 2][n] = v.z; atg_[k + 3][n] = v.w;
        }
        for (int it = tid; it < 128 * BKQ; it += 256) {
            int c = it & 127, qq = it >> 7;
            float4 v = make_float4(0.f, 0.f, 0.f, 0.f);
            if (c < D) v = *(const float4*)&whn[c * D + kc + qq * 4];
            int k = qq * 4;
            wts_[k][c] = v.x; wts_[k + 1][c] = v.y; wts_[k + 2][c] = v.z; wts_[k + 3][c] = v.w;
        }
        __syncthreads();
#pragma unroll
        for (int k = 0; k < BK; ++k) {
            float4 a0 = *(const float4*)&atg_[k][an];
            float4 w0 = *(const float4*)&wts_[k][c0];
            float4 w1 = *(const float4*)&wts_[k][64 + c0];
            float av[4] = {a0.x, a0.y, a0.z, a0.w};
            float wv[8] = {w0.x, w0.y, w0.z, w0.w, w1.x, w1.y, w1.z, w1.w};
#pragma unroll
            for (int i = 0; i < 4; ++i)
#pragma unroll
                for (int j = 0; j < 8; ++j) accn[i][j] += av[i] * wv[j];
        }
    }
#pragma unroll
    for (int j = 0; j < 8; ++j) {
        float bn = cval[j] ? bhh[2 * D + cch[j]] : 0.0f;
#pragma unroll
        for (int i = 0; i < 4; ++i) r[i][j] = r[i][j] * (accn[i][j] + bn);  // r <- r*h_n
    }

    // ---------------- phase 3: i_n (K=120 over vbl) ----------------
#pragma unroll
    for (int i = 0; i < 4; ++i)
#pragma unroll
        for (int j = 0; j < 8; ++j) accn[i][j] = 0.0f;

    const float* win = wih + 2 * D * D;
    for (int kc = 0; kc < D; kc += BK) {
        __syncthreads();
        for (int it = tid; it < 64 * BKQ; it += 256) {
            int n = it & 63, qq = it >> 6;
            int gn = nbase + n;
            float4 v = make_float4(0.f, 0.f, 0.f, 0.f);
            if (gn < M) v = *(const float4*)&vbl[(size_t)gn * D + kc + qq * 4];
            int k = qq * 4;
            atg_[k][n] = v.x; atg_[k + 1][n] = v.y; atg_[k + 2][n] = v.z; atg_[k + 3][n] = v.w;
        }
        for (int it = tid; it < 128 * BKQ; it += 256) {
            int c = it & 127, qq = it >> 7;
            float4 v = make_float4(0.f, 0.f, 0.f, 0.f);
            if (c < D) v = *(const float4*)&win[c * D + kc + qq * 4];
            int k = qq * 4;
            wts_[k][c] = v.x; wts_[k + 1][c] = v.y; wts_[k + 2][c] = v.z; wts_[k + 3][c] = v.w;
        }
        __syncthreads();
#pragma unroll
        for (int k = 0; k < BK; ++k) {
            float4 a0 = *(const float4*)&atg_[k][an];
            float4 w0 = *(const float4*)&wts_[k][c0];
            float4 w1 = *(const float4*)&wts_[k][64 + c0];
            float av[4] = {a0.x, a0.y, a0.z, a0.w};
            float wv[8] = {w0.x, w0.y, w0.z, w0.w, w1.x, w1.y, w1.z, w1.w};
#pragma unroll
            for (int i = 0; i < 4; ++i)
#pragma unroll
                for (int j = 0; j < 8; ++j) accn[i][j] += av[i] * wv[j];
        }
    }

    // ---------------- epilogue ----------------
#pragma unroll
    for (int i = 0; i < 4; ++i) {
        int gn = nbase + an + i;
        if (gn >= M) continue;
        float4 h0 = *(const float4*)&h[(size_t)gn * D + c0];
        float hv0[4] = {h0.x, h0.y, h0.z, h0.w};
        float o[4];
#pragma unroll
        for (int j = 0; j < 4; ++j) {
            float bn = bih[2 * D + cch[j]];
            float nv = tanhf_(accn[i][j] + bn + r[i][j]);
            o[j] = (1.0f - zz[i][j]) * nv + zz[i][j] * hv0[j];
        }
        *(float4*)&out[(size_t)gn * D + c0] = make_float4(o[0], o[1], o[2], o[3]);
        if (tc < 14) {
            float4 h1 = *(const float4*)&h[(size_t)gn * D + 64 + c0];
            float hv1[4] = {h1.x, h1.y, h1.z, h1.w};
#pragma unroll
            for (int j = 0; j < 4; ++j) {
                float bn = bih[2 * D + cch[4 + j]];
                float nv = tanhf_(accn[i][4 + j] + bn + r[i][4 + j]);
                o[j] = (1.0f - zz[i][4 + j]) * nv + zz[i][4 + j] * hv1[j];
            }
            *(float4*)&out[(size_t)gn * D + 64 + c0] = make_float4(o[0], o[1], o[2], o[3]);
        }
    }
}

extern "C" void kernel_launch(void* const* d_in, const int* in_sizes, int n_in,
                              void* d_out, int out_size, void* d_ws, size_t ws_size,
                              hipStream_t stream) {
    const float* va = (const float*)d_in[0];
    const float* vb = (const float*)d_in[1];
    const float* W_L = (const float*)d_in[2];
    const float* b_L = (const float*)d_in[3];
    const float* W_se1 = (const float*)d_in[4];
    const float* W_se2 = (const float*)d_in[5];
    const float* W_hw = (const float*)d_in[6];
    const float* b_hw = (const float*)d_in[7];
    const float* w_ih = (const float*)d_in[8];
    const float* w_hh = (const float*)d_in[9];
    const float* b_ih = (const float*)d_in[10];
    const float* b_hh = (const float*)d_in[11];
    const int* seg_a = (const int*)d_in[12];
    const int* seg_b = (const int*)d_in[13];

    int Na = in_sizes[0] / D;
    int Nb = in_sizes[1] / D;
    float* out = (float*)d_out;

    char* ws = (char*)d_ws;
    size_t offs = 0;
    auto alloc = [&](size_t bytes) -> void* {
        void* p = ws + offs;
        offs = (offs + bytes + 255) & ~(size_t)255;
        return p;
    };
    float* sbuf = (float*)alloc((size_t)Na * D * sizeof(float));  // s, later reused as h
    float* vbl = (float*)alloc((size_t)Nb * D * sizeof(float));
    float* wse = (float*)alloc((size_t)GNUM * D * sizeof(float));
    float* pooled = (float*)alloc((size_t)GNUM * D * sizeof(float));
    float* ahw = (float*)alloc((size_t)GNUM * D * sizeof(float));
    int* start_a = (int*)alloc((GNUM + 1) * sizeof(int));
    int* start_b = (int*)alloc((GNUM + 1) * sizeof(int));
    float* hbuf = sbuf;

    int obl = (GNUM + 1 + 255) / 256;
    offsets_kernel<<<obl, 256, 0, stream>>>(seg_a, Na, start_a);
    offsets_kernel<<<obl, 256, 0, stream>>>(seg_b, Nb, start_b);

    // s = va @ W_L^T + b_L
    gemm_lin<0><<<(Na + 127) / 128, 256, 0, stream>>>(va, W_L, b_L, sbuf, Na, nullptr, nullptr);
    // SE weights per graph
    se_kernel<<<GNUM, 128, 0, stream>>>(sbuf, start_a, W_se1, W_se2, wse);
    // pooled per graph
    pool_kernel<<<GNUM, 256, 0, stream>>>(sbuf, start_a, wse, pooled);
    // a_hw = pooled @ W_hw^T + b_hw  (tiny GEMM, M=2048)
    gemm_lin<0><<<(GNUM + 127) / 128, 256, 0, stream>>>(pooled, W_hw, b_hw, ahw, GNUM, nullptr, nullptr);
    // vb_l = vb @ W_L^T + b_L
    gemm_lin<0><<<(Nb + 127) / 128, 256, 0, stream>>>(vb, W_L, b_L, vbl, Nb, nullptr, nullptr);
    // highway: h = z*b + (1-z)*a  (writes into sbuf, which is dead now)
    gemm_lin<1><<<(Nb + 127) / 128, 256, 0, stream>>>(vbl, W_hw, b_hw, hbuf, Nb, ahw, seg_b);
    // GRU
    gru_kernel<<<(Nb + 63) / 64, 256, 0, stream>>>(vbl, hbuf, w_ih, w_hh, b_ih, b_hh, out, Nb);
}

// Round 10
// 721.454 us; speedup vs baseline: 2.5809x; 2.5809x over previous
//
#include <hip/hip_runtime.h>
#include <math.h>

#define D 120
#define GNUM 2048
#define RSE 15

// NOTE: Na = Nb = 200000 (multiple of 64) and G = 2048 (multiple of 64) are
// relied upon: all MFMA GEMM blocks are full 64-row tiles.

typedef __attribute__((ext_vector_type(8))) short bf16x8;   // 8 bf16 = 4 VGPRs
typedef __attribute__((ext_vector_type(4))) float f32x4;    // MFMA acc

#define MFMA(a, b, c) __builtin_amdgcn_mfma_f32_16x16x32_bf16((a), (b), (c), 0, 0, 0)

__device__ __forceinline__ float sigmoidf_(float x) { return 1.0f / (1.0f + __expf(-x)); }
__device__ __forceinline__ float tanhf_(float x) { return 1.0f - 2.0f / (1.0f + __expf(2.0f * x)); }

__device__ __forceinline__ ushort f2bf(float x) {
    union { float f; uint u; } c; c.f = x;
    uint r = c.u + 0x7FFFu + ((c.u >> 16) & 1u);   // RNE
    return (ushort)(r >> 16);
}
__device__ __forceinline__ float bf2f(ushort h) {
    union { uint u; float f; } c; c.u = ((uint)h) << 16; return c.f;
}
__device__ __forceinline__ void split8(const float* v, bf16x8& hv, bf16x8& lv) {
#pragma unroll
    for (int j = 0; j < 8; ++j) {
        ushort hb = f2bf(v[j]);
        hv[j] = (short)hb;
        lv[j] = (short)f2bf(v[j] - bf2f(hb));
    }
}

// start[g] = first i with seg[i] >= g; start[G] = n
__global__ void offsets_kernel(const int* __restrict__ seg, int n, int* __restrict__ start) {
    int g = blockIdx.x * blockDim.x + threadIdx.x;
    if (g > GNUM) return;
    int lo = 0, hi = n;
    while (lo < hi) {
        int mid = (lo + hi) >> 1;
        if (seg[mid] < g) lo = mid + 1; else hi = mid;
    }
    start[g] = lo;
}

// ---- weight pre-split: W[120][120] -> frag-major hi/lo planes, padded 128x128.
// unit index = (nt*4 + ch)*64 + lane ; element j: col = nt*16+(lane&15),
// k = ch*32 + (lane>>4)*8 + j.
__global__ void wsplit_lin(const float* __restrict__ W, bf16x8* __restrict__ whi,
                           bf16x8* __restrict__ wlo) {
    int t = blockIdx.x * 256 + threadIdx.x;
    if (t >= 8 * 4 * 64) return;
    int lane = t & 63;
    int nc = t >> 6;
    int ch = nc & 3, nt = nc >> 2;
    int col = nt * 16 + (lane & 15);
    int k0 = ch * 32 + ((lane >> 4) << 3);
    float v[8];
#pragma unroll
    for (int j = 0; j < 8; ++j) {
        int k = k0 + j;
        v[j] = (col < D && k < D) ? W[col * D + k] : 0.0f;
    }
    bf16x8 hv, lv; split8(v, hv, lv);
    whi[t] = hv; wlo[t] = lv;
}

// ---- GRU packed weights: 512 cols x 256 K (gate blocks r,z,i_n,h_n at col
// offsets 0,128,256,384; K = [vbl(120) | h(120) | pad]).
__global__ void wsplit_gru(const float* __restrict__ wih, const float* __restrict__ whh,
                           bf16x8* __restrict__ whi, bf16x8* __restrict__ wlo) {
    int t = blockIdx.x * 256 + threadIdx.x;
    if (t >= 32 * 8 * 64) return;
    int lane = t & 63;
    int nc = t >> 6;
    int ch = nc & 7, nt = nc >> 3;
    int g = nt >> 3, sub = nt & 7;
    int dcol = sub * 16 + (lane & 15);
    int k0 = ch * 32 + ((lane >> 4) << 3);
    float v[8];
#pragma unroll
    for (int j = 0; j < 8; ++j) {
        int k = k0 + j;
        float val = 0.0f;
        if (dcol < D) {
            if (g == 0) {          // r gate: wih[d] over vbl, whh[d] over h
                val = (k < D) ? wih[dcol * D + k] : ((k < 2 * D) ? whh[dcol * D + (k - D)] : 0.0f);
            } else if (g == 1) {   // z gate
                int rr = D + dcol;
                val = (k < D) ? wih[rr * D + k] : ((k < 2 * D) ? whh[rr * D + (k - D)] : 0.0f);
            } else if (g == 2) {   // i_n: wih[240+d] over vbl only
                val = (k < D) ? wih[(2 * D + dcol) * D + k] : 0.0f;
            } else {               // h_n: whh[240+d] over h only
                val = (k >= D && k < 2 * D) ? whh[(2 * D + dcol) * D + (k - D)] : 0.0f;
            }
        }
        v[j] = val;
    }
    bf16x8 hv, lv; split8(v, hv, lv);
    whi[t] = hv; wlo[t] = lv;
}

// ---- MFMA linear: C[M][120] = act(A) @ W^T + bias (MODE 0) or highway
// epilogue vs ahw[seg] (MODE 1, act = tanh). Block: 64 rows, 4 waves x 32 cols.
template <int MODE>
__global__ __launch_bounds__(256)
void lin_mfma(const float* __restrict__ A, const bf16x8* __restrict__ whi,
              const bf16x8* __restrict__ wlo, const float* __restrict__ bias,
              float* __restrict__ Cout, int M,
              const float* __restrict__ ahw, const int* __restrict__ seg) {
    __shared__ __align__(16) short sAh[16 * 64 * 8];   // hi plane, k-group-major units
    __shared__ __align__(16) short sAl[16 * 64 * 8];   // lo plane
    int tid = threadIdx.x;
    int rowbase = blockIdx.x * 64;

    // stage + split: unit u -> row = bits1..6, kg = bit0 | bits7..9<<1
    for (int i = 0; i < 4; ++i) {
        int u = i * 256 + tid;
        int row = (u >> 1) & 63;
        int kg = (u & 1) | (((u >> 7) & 7) << 1);
        float v[8];
        if (kg < 15) {
            const float* src = A + (size_t)(rowbase + row) * D + kg * 8;
            float4 x0 = *(const float4*)src;
            float4 x1 = *(const float4*)(src + 4);
            v[0] = x0.x; v[1] = x0.y; v[2] = x0.z; v[3] = x0.w;
            v[4] = x1.x; v[5] = x1.y; v[6] = x1.z; v[7] = x1.w;
        } else {
#pragma unroll
            for (int j = 0; j < 8; ++j) v[j] = 0.0f;
        }
        if (MODE == 1) {
#pragma unroll
            for (int j = 0; j < 8; ++j) v[j] = tanhf_(v[j]);
        }
        bf16x8 hv, lv; split8(v, hv, lv);
        ((bf16x8*)sAh)[kg * 64 + row] = hv;
        ((bf16x8*)sAl)[kg * 64 + row] = lv;
    }
    __syncthreads();

    int lane = tid & 63, w = tid >> 6;
    f32x4 acc[4][2];
#pragma unroll
    for (int rt = 0; rt < 4; ++rt)
#pragma unroll
        for (int tt = 0; tt < 2; ++tt) acc[rt][tt] = (f32x4){0.f, 0.f, 0.f, 0.f};

#pragma unroll
    for (int ch = 0; ch < 4; ++ch) {
        bf16x8 ah[4], al[4];
#pragma unroll
        for (int rt = 0; rt < 4; ++rt) {
            int ui = (ch * 4 + (lane >> 4)) * 64 + rt * 16 + (lane & 15);
            ah[rt] = ((const bf16x8*)sAh)[ui];
            al[rt] = ((const bf16x8*)sAl)[ui];
        }
#pragma unroll
        for (int tt = 0; tt < 2; ++tt) {
            int nt = 2 * w + tt;
            int wb = (nt * 4 + ch) * 64 + lane;
            bf16x8 wh = whi[wb], wl = wlo[wb];
#pragma unroll
            for (int rt = 0; rt < 4; ++rt) {
                acc[rt][tt] = MFMA(ah[rt], wh, acc[rt][tt]);
                acc[rt][tt] = MFMA(al[rt], wh, acc[rt][tt]);
                acc[rt][tt] = MFMA(ah[rt], wl, acc[rt][tt]);
            }
        }
    }

    // epilogue: D-layout col = lane&15, row = (lane>>4)*4 + p
    int dd[2]; bool dok[2]; float bb[2];
#pragma unroll
    for (int tt = 0; tt < 2; ++tt) {
        int d = (2 * w + tt) * 16 + (lane & 15);
        dd[tt] = d; dok[tt] = (d < D);
        bb[tt] = dok[tt] ? bias[d] : 0.0f;
    }
#pragma unroll
    for (int rt = 0; rt < 4; ++rt)
#pragma unroll
        for (int p = 0; p < 4; ++p) {
            int row = rt * 16 + ((lane >> 4) << 2) + p;
            size_t gn = (size_t)rowbase + row;
            if (MODE == 0) {
#pragma unroll
                for (int tt = 0; tt < 2; ++tt)
                    if (dok[tt]) Cout[gn * D + dd[tt]] = acc[rt][tt][p] + bb[tt];
            } else {
                int g = seg[gn];
#pragma unroll
                for (int tt = 0; tt < 2; ++tt) {
                    if (!dok[tt]) continue;
                    float b = acc[rt][tt][p] + bb[tt];
                    float a = ahw[(size_t)g * D + dd[tt]];
                    float z = sigmoidf_(a + b);
                    Cout[gn * D + dd[tt]] = z * b + (1.0f - z) * a;
                }
            }
        }
}

// ---- fused GRU via one MFMA GEMM: N = 512 (gates r,z,i_n,h_n at 128-col
// blocks), K = 256 ([vbl|h|pad]). Wave w owns d-range [32w, 32w+32) across all
// four gate blocks -> full epilogue in-registers.
__global__ __launch_bounds__(256)
void gru_mfma(const float* __restrict__ vbl, const float* __restrict__ h,
              const bf16x8* __restrict__ whi, const bf16x8* __restrict__ wlo,
              const float* __restrict__ bih, const float* __restrict__ bhh,
              float* __restrict__ out, int M) {
    __shared__ __align__(16) short sAh[32 * 64 * 8];   // 32 KB
    __shared__ __align__(16) short sAl[32 * 64 * 8];   // 32 KB
    int tid = threadIdx.x;
    int rowbase = blockIdx.x * 64;

    for (int i = 0; i < 8; ++i) {
        int u = i * 256 + tid;
        int row = (u >> 1) & 63;
        int kg = (u & 1) | (((u >> 7) & 15) << 1);
        float v[8];
        const float* src = nullptr;
        if (kg < 15) src = vbl + (size_t)(rowbase + row) * D + kg * 8;
        else if (kg < 30) src = h + (size_t)(rowbase + row) * D + (kg - 15) * 8;
        if (src) {
            float4 x0 = *(const float4*)src;
            float4 x1 = *(const float4*)(src + 4);
            v[0] = x0.x; v[1] = x0.y; v[2] = x0.z; v[3] = x0.w;
            v[4] = x1.x; v[5] = x1.y; v[6] = x1.z; v[7] = x1.w;
        } else {
#pragma unroll
            for (int j = 0; j < 8; ++j) v[j] = 0.0f;
        }
        bf16x8 hv, lv; split8(v, hv, lv);
        ((bf16x8*)sAh)[kg * 64 + row] = hv;
        ((bf16x8*)sAl)[kg * 64 + row] = lv;
    }
    __syncthreads();

    int lane = tid & 63, w = tid >> 6;
    f32x4 acc[4][4][2];   // [row-tile][gate][col-sub]
#pragma unroll
    for (int rt = 0; rt < 4; ++rt)
#pragma unroll
        for (int g = 0; g < 4; ++g)
#pragma unroll
            for (int tt = 0; tt < 2; ++tt) acc[rt][g][tt] = (f32x4){0.f, 0.f, 0.f, 0.f};

#pragma unroll
    for (int ch = 0; ch < 8; ++ch) {
        bf16x8 ah[4], al[4];
#pragma unroll
        for (int rt = 0; rt < 4; ++rt) {
            int ui = (ch * 4 + (lane >> 4)) * 64 + rt * 16 + (lane & 15);
            ah[rt] = ((const bf16x8*)sAh)[ui];
            al[rt] = ((const bf16x8*)sAl)[ui];
        }
#pragma unroll
        for (int g = 0; g < 4; ++g)
#pragma unroll
            for (int tt = 0; tt < 2; ++tt) {
                int nt = g * 8 + 2 * w + tt;
                int wb = (nt * 8 + ch) * 64 + lane;
                bf16x8 wh = whi[wb], wl = wlo[wb];
#pragma unroll
                for (int rt = 0; rt < 4; ++rt) {
                    acc[rt][g][tt] = MFMA(ah[rt], wh, acc[rt][g][tt]);
                    acc[rt][g][tt] = MFMA(al[rt], wh, acc[rt][g][tt]);
                    acc[rt][g][tt] = MFMA(ah[rt], wl, acc[rt][g][tt]);
                }
            }
    }

    // epilogue
    int dd[2]; bool dok[2];
    float br[2], bz[2], bnn[2], bhn[2];
#pragma unroll
    for (int tt = 0; tt < 2; ++tt) {
        int d = (2 * w + tt) * 16 + (lane & 15);
        dd[tt] = d; dok[tt] = (d < D);
        if (dok[tt]) {
            br[tt] = bih[d] + bhh[d];
            bz[tt] = bih[D + d] + bhh[D + d];
            bnn[tt] = bih[2 * D + d];
            bhn[tt] = bhh[2 * D + d];
        } else { br[tt] = bz[tt] = bnn[tt] = bhn[tt] = 0.0f; }
    }
#pragma unroll
    for (int rt = 0; rt < 4; ++rt)
#pragma unroll
        for (int p = 0; p < 4; ++p) {
            int row = rt * 16 + ((lane >> 4) << 2) + p;
            size_t gn = (size_t)rowbase + row;
#pragma unroll
            for (int tt = 0; tt < 2; ++tt) {
                if (!dok[tt]) continue;
                int d = dd[tt];
                float hv = h[gn * D + d];
                float rr = sigmoidf_(acc[rt][0][tt][p] + br[tt]);
                float zv = sigmoidf_(acc[rt][1][tt][p] + bz[tt]);
                float nn = tanhf_(acc[rt][2][tt][p] + bnn[tt] + rr * (acc[rt][3][tt][p] + bhn[tt]));
                out[gn * D + d] = (1.0f - zv) * nn + zv * hv;
            }
        }
}

// Per-graph: channel average of s -> SE MLP -> w[g][120]
__global__ __launch_bounds__(128)
void se_kernel(const float* __restrict__ s, const int* __restrict__ start,
               const float* __restrict__ Wse1, const float* __restrict__ Wse2,
               float* __restrict__ wout) {
    int g = blockIdx.x;
    int i0 = start[g], i1 = start[g + 1];
    int t = threadIdx.x;
    __shared__ float avg_[D];
    __shared__ float t_[RSE];
    if (t < D) {
        float sum = 0.0f;
        for (int i = i0; i < i1; ++i) sum += s[(size_t)i * D + t];
        float cnt = (float)(i1 - i0);
        avg_[t] = sum / fmaxf(cnt, 1.0f);
    }
    __syncthreads();
    if (t < RSE) {
        float a = 0.0f;
        for (int j = 0; j < D; ++j) a += avg_[j] * Wse1[t * D + j];
        t_[t] = fmaxf(a, 0.0f);
    }
    __syncthreads();
    if (t < D) {
        float a = 0.0f;
#pragma unroll
        for (int k = 0; k < RSE; ++k) a += t_[k] * Wse2[t * RSE + k];
        wout[(size_t)g * D + t] = sigmoidf_(a);
    }
}

// Per-graph: A = sum s_i*mean_c(s_i*w), B = sum sigmoid(s_i), pooled = A*B
__global__ __launch_bounds__(256)
void pool_kernel(const float* __restrict__ s, const int* __restrict__ start,
                 const float* __restrict__ wse, float* __restrict__ pooled) {
    int g = blockIdx.x;
    int i0 = start[g], i1 = start[g + 1];
    int t = threadIdx.x;
    int lane = t & 63, wv = t >> 6;
    __shared__ float wl_[D];
    __shared__ float red_[8][D];
    if (t < D) wl_[t] = wse[(size_t)g * D + t];
    __syncthreads();
    float w0 = wl_[lane];
    float w1 = (lane < D - 64) ? wl_[lane + 64] : 0.0f;
    float A0 = 0, A1 = 0, B0 = 0, B1 = 0;
    for (int i = i0 + wv; i < i1; i += 4) {
        const float* row = s + (size_t)i * D;
        float s0 = row[lane];
        float s1 = (lane < D - 64) ? row[lane + 64] : 0.0f;
        float d = s0 * w0 + s1 * w1;
#pragma unroll
        for (int off = 32; off > 0; off >>= 1) d += __shfl_xor(d, off);
        float m = d * (1.0f / D);
        A0 += s0 * m;
        A1 += s1 * m;
        B0 += sigmoidf_(s0);
        B1 += sigmoidf_(s1);
    }
    red_[wv][lane] = A0;
    red_[4 + wv][lane] = B0;
    if (lane < D - 64) {
        red_[wv][lane + 64] = A1;
        red_[4 + wv][lane + 64] = B1;
    }
    __syncthreads();
    if (t < D) {
        float A = red_[0][t] + red_[1][t] + red_[2][t] + red_[3][t];
        float B = red_[4][t] + red_[5][t] + red_[6][t] + red_[7][t];
        pooled[(size_t)g * D + t] = A * B;
    }
}

extern "C" void kernel_launch(void* const* d_in, const int* in_sizes, int n_in,
                              void* d_out, int out_size, void* d_ws, size_t ws_size,
                              hipStream_t stream) {
    const float* va = (const float*)d_in[0];
    const float* vb = (const float*)d_in[1];
    const float* W_L = (const float*)d_in[2];
    const float* b_L = (const float*)d_in[3];
    const float* W_se1 = (const float*)d_in[4];
    const float* W_se2 = (const float*)d_in[5];
    const float* W_hw = (const float*)d_in[6];
    const float* b_hw = (const float*)d_in[7];
    const float* w_ih = (const float*)d_in[8];
    const float* w_hh = (const float*)d_in[9];
    const float* b_ih = (const float*)d_in[10];
    const float* b_hh = (const float*)d_in[11];
    const int* seg_a = (const int*)d_in[12];
    const int* seg_b = (const int*)d_in[13];

    int Na = in_sizes[0] / D;
    int Nb = in_sizes[1] / D;
    float* out = (float*)d_out;

    char* ws = (char*)d_ws;
    size_t offs = 0;
    auto alloc = [&](size_t bytes) -> void* {
        void* p = ws + offs;
        offs = (offs + bytes + 255) & ~(size_t)255;
        return p;
    };
    float* sbuf = (float*)alloc((size_t)Na * D * sizeof(float));   // s, reused as h
    float* vbl = (float*)alloc((size_t)Nb * D * sizeof(float));
    float* wse = (float*)alloc((size_t)GNUM * D * sizeof(float));
    float* pooled = (float*)alloc((size_t)GNUM * D * sizeof(float));
    float* ahw = (float*)alloc((size_t)GNUM * D * sizeof(float));
    int* start_a = (int*)alloc((GNUM + 1) * sizeof(int));
    int* start_b = (int*)alloc((GNUM + 1) * sizeof(int));
    bf16x8* wlf_hi = (bf16x8*)alloc(8 * 4 * 64 * 16);     // W_L frags
    bf16x8* wlf_lo = (bf16x8*)alloc(8 * 4 * 64 * 16);
    bf16x8* whwf_hi = (bf16x8*)alloc(8 * 4 * 64 * 16);    // W_hw frags
    bf16x8* whwf_lo = (bf16x8*)alloc(8 * 4 * 64 * 16);
    bf16x8* wgf_hi = (bf16x8*)alloc(32 * 8 * 64 * 16);    // GRU packed frags
    bf16x8* wgf_lo = (bf16x8*)alloc(32 * 8 * 64 * 16);
    float* hbuf = sbuf;

    int obl = (GNUM + 1 + 255) / 256;
    offsets_kernel<<<obl, 256, 0, stream>>>(seg_a, Na, start_a);
    offsets_kernel<<<obl, 256, 0, stream>>>(seg_b, Nb, start_b);

    wsplit_lin<<<8, 256, 0, stream>>>(W_L, wlf_hi, wlf_lo);
    wsplit_lin<<<8, 256, 0, stream>>>(W_hw, whwf_hi, whwf_lo);
    wsplit_gru<<<64, 256, 0, stream>>>(w_ih, w_hh, wgf_hi, wgf_lo);

    // s = va @ W_L^T + b_L
    lin_mfma<0><<<Na / 64, 256, 0, stream>>>(va, wlf_hi, wlf_lo, b_L, sbuf, Na, nullptr, nullptr);
    // SE weights per graph
    se_kernel<<<GNUM, 128, 0, stream>>>(sbuf, start_a, W_se1, W_se2, wse);
    // pooled per graph
    pool_kernel<<<GNUM, 256, 0, stream>>>(sbuf, start_a, wse, pooled);
    // a_hw = pooled @ W_hw^T + b_hw
    lin_mfma<0><<<GNUM / 64, 256, 0, stream>>>(pooled, whwf_hi, whwf_lo, b_hw, ahw, GNUM, nullptr, nullptr);
    // vb_l = vb @ W_L^T + b_L
    lin_mfma<0><<<Nb / 64, 256, 0, stream>>>(vb, wlf_hi, wlf_lo, b_L, vbl, Nb, nullptr, nullptr);
    // highway: h = z*b + (1-z)*a   (b = tanh(vbl) @ W_hw^T + b_hw, a = ahw[seg_b])
    lin_mfma<1><<<Nb / 64, 256, 0, stream>>>(vbl, whwf_hi, whwf_lo, b_hw, hbuf, Nb, ahw, seg_b);
    // GRU
    gru_mfma<<<Nb / 64, 256, 0, stream>>>(vbl, hbuf, wgf_hi, wgf_lo, b_ih, b_hh, out, Nb);
}